// Round 5
// baseline (31.647 us; speedup 1.0000x reference)
//
#include <hip/hip_runtime.h>

// Problem constants
#define BB     4096
#define NNODE  177
#define NSUB   36
#define KN     6
#define HH     128
#define OBSD   500
#define TB     32          // batches per block = 2 x M=16 MFMA tiles
#define NTHR   512         // 8 waves, 2/SIMD

typedef unsigned short ushort_t;
typedef __attribute__((ext_vector_type(4))) float f32x4;
typedef __attribute__((ext_vector_type(8))) short s16x8;
typedef __attribute__((ext_vector_type(4))) unsigned short u16x4;

#define MFMA16(a, b, c) __builtin_amdgcn_mfma_f32_16x16x32_bf16((a), (b), (c), 0, 0, 0)

__device__ __forceinline__ ushort_t f2bf(float f) {
    unsigned u = __float_as_uint(f);
    u += 0x7FFFu + ((u >> 16) & 1u);   // RNE
    return (ushort_t)(u >> 16);
}
__device__ __forceinline__ u16x4 f2bf4(float4 v) {
    u16x4 o; o.x = f2bf(v.x); o.y = f2bf(v.y); o.z = f2bf(v.z); o.w = f2bf(v.w);
    return o;
}

// B-fragment on the fly: bf16x8 of W[(k+j)*128 + col], j=0..7 (column slice;
// 16 lanes of a g-group cover one 64B L2 line per j). RNE via v_cvt_pk_bf16_f32.
__device__ __forceinline__ s16x8 ldB8(const float* __restrict__ W, int k, int col) {
    const float* p = W + k * HH + col;
    float w0 = p[0],      w1 = p[HH],     w2 = p[2 * HH], w3 = p[3 * HH];
    float w4 = p[4 * HH], w5 = p[5 * HH], w6 = p[6 * HH], w7 = p[7 * HH];
    union { unsigned u[4]; s16x8 v; } U;
    asm("v_cvt_pk_bf16_f32 %0, %1, %2" : "=v"(U.u[0]) : "v"(w0), "v"(w1));
    asm("v_cvt_pk_bf16_f32 %0, %1, %2" : "=v"(U.u[1]) : "v"(w2), "v"(w3));
    asm("v_cvt_pk_bf16_f32 %0, %1, %2" : "=v"(U.u[2]) : "v"(w4), "v"(w5));
    asm("v_cvt_pk_bf16_f32 %0, %1, %2" : "=v"(U.u[3]) : "v"(w6), "v"(w7));
    return U.v;
}
__device__ __forceinline__ s16x8 ldB8m(const float* __restrict__ W, int k, int col, int kmax) {
    float w[8];
    #pragma unroll
    for (int j = 0; j < 8; ++j) w[j] = (k + j < kmax) ? W[(k + j) * HH + col] : 0.f;
    union { unsigned u[4]; s16x8 v; } U;
    #pragma unroll
    for (int j = 0; j < 4; ++j)
        asm("v_cvt_pk_bf16_f32 %0, %1, %2" : "=v"(U.u[j]) : "v"(w[2 * j]), "v"(w[2 * j + 1]));
    return U.v;
}

// ---------------------------------------------------------------------------
// Single fused kernel. Block = 32 batches (two M=16 tiles m=0,1), 8 waves;
// wave w owns cols [16w,16w+16); every B-fragment feeds both m-tiles.
// Weights consumed directly from f32 global (L2-hot), converted in-register.
// ---------------------------------------------------------------------------
__global__ void __launch_bounds__(NTHR, 2) k_main(
    const float* __restrict__ org_obs, const float* __restrict__ node_emb,
    const float* __restrict__ subst,   const int* __restrict__ sub_choice,
    const int* __restrict__ sub_map,   const float* __restrict__ Wproj,
    const float* __restrict__ bproj,   const float* __restrict__ W1,
    const float* __restrict__ a_src1,  const float* __restrict__ a_dst1,
    const float* __restrict__ b1,      const float* __restrict__ W2,
    const float* __restrict__ a_src2,  const float* __restrict__ a_dst2,
    const float* __restrict__ b2,      float* __restrict__ out) {

    // LDS map (bytes):
    //   s_a     @0      [32][1280B] bf16 swz = 40960  (obs 0..499|0|sub cols 512..639)
    //   s_nodes @40960  [192][256B] bf16 swz = 49152  (row = s*32+b)
    //   s_x     @90112  [32][256B]  bf16 swz =  8192
    //   s_h     @0 (overlay, after sync) [192][133 f32] = 102144
    //   s_e     @102144 [32][6][8] f32      =  6144   (0-3 es, 4-7 ed)
    //   s_alpha @108288 f32[32*145]         = 18560
    //   s_p     @126848 f32[8][32][6]       =  6144
    __shared__ __align__(16) char smem[132992];
    float* s_h     = (float*)smem;
    float* s_e     = (float*)(smem + 102144);
    float* s_alpha = (float*)(smem + 108288);
    float* s_p     = (float*)(smem + 126848);

    const int t   = threadIdx.x;
    const int gb0 = blockIdx.x * TB;

    // ---- staging: obs+sub -> s_a (swz); nodes -> regs (16 lanes per batch)
    float4 nreg0[6], nreg1[6];
    {
        const int b = t >> 4, l = t & 15;
        const float* orow = org_obs + (size_t)(gb0 + b) * OBSD;
        int sub = sub_choice[gb0 + b];
        const int* emap = sub_map + sub * KN;
        #pragma unroll
        for (int s = 0; s < 6; ++s) {
            const float4* nrow = (const float4*)(node_emb +
                ((size_t)(gb0 + b) * NNODE + emap[s]) * HH);
            nreg0[s] = nrow[l];
            nreg1[s] = nrow[16 + l];
        }
        const int swz = (b & 7) << 4;
        #pragma unroll
        for (int it = 0; it < 8; ++it) {
            int idx = it * 16 + l;
            u16x4 v = {0, 0, 0, 0};
            if (idx < 125) v = f2bf4(((const float4*)orow)[idx]);
            *(u16x4*)(smem + b * 1280 + ((idx * 8) ^ swz)) = v;
        }
        const float4* srow = (const float4*)(subst + ((size_t)(gb0 + b) * NSUB + sub) * HH);
        *(u16x4*)(smem + b * 1280 + ((1024 + l * 8) ^ swz)) = f2bf4(srow[l]);
        *(u16x4*)(smem + b * 1280 + ((1024 + (16 + l) * 8) ^ swz)) = f2bf4(srow[16 + l]);
    }

    const int w = t >> 6, ln = t & 63, r16 = ln & 15, g = ln >> 4;
    const int col = w * 16 + r16;
    const int rswz = (r16 & 7) << 4;

    // ---- prefetch phase-1 B-fragments kk=0..5 (L2 latency hides under staging)
    s16x8 pf0 = ldB8(Wproj, 0 * 32 + g * 8, col);
    s16x8 pf1 = ldB8(Wproj, 1 * 32 + g * 8, col);
    s16x8 pf2 = ldB8(Wproj, 2 * 32 + g * 8, col);
    s16x8 pf3 = ldB8(Wproj, 3 * 32 + g * 8, col);
    s16x8 pf4 = ldB8(Wproj, 4 * 32 + g * 8, col);
    s16x8 pf5 = ldB8(Wproj, 5 * 32 + g * 8, col);
    __syncthreads();

    // ---- phase 1: obs @ Wproj (K=512, rows 500..511 masked), both m-tiles
    f32x4 acc1_0 = {0.f, 0.f, 0.f, 0.f}, acc1_1 = {0.f, 0.f, 0.f, 0.f};
    #pragma unroll
    for (int kk = 0; kk < 16; ++kk) {
        s16x8 bf;
        if      (kk == 0) bf = pf0;
        else if (kk == 1) bf = pf1;
        else if (kk == 2) bf = pf2;
        else if (kk == 3) bf = pf3;
        else if (kk == 4) bf = pf4;
        else if (kk == 5) bf = pf5;
        else if (kk < 15) bf = ldB8(Wproj, kk * 32 + g * 8, col);
        else              bf = ldB8m(Wproj, kk * 32 + g * 8, col, OBSD);
        s16x8 af0 = *(const s16x8*)(smem + r16 * 1280 + ((kk * 64 + g * 16) ^ rswz));
        acc1_0 = MFMA16(af0, bf, acc1_0);
        s16x8 af1 = *(const s16x8*)(smem + (16 + r16) * 1280 + ((kk * 64 + g * 16) ^ rswz));
        acc1_1 = MFMA16(af1, bf, acc1_1);
    }

    // ---- obs_repr(+bproj) -> s_x bf16; node regs -> s_nodes
    {
        float bp = bproj[col];
        #pragma unroll
        for (int rg = 0; rg < 4; ++rg) {
            int b0 = g * 4 + rg, b1i = 16 + g * 4 + rg;
            *(ushort_t*)(smem + 90112 + b0 * 256 + ((col * 2) ^ ((b0 & 7) << 4))) =
                f2bf(acc1_0[rg] + bp);
            *(ushort_t*)(smem + 90112 + b1i * 256 + ((col * 2) ^ ((b1i & 7) << 4))) =
                f2bf(acc1_1[rg] + bp);
        }
    }
    {
        const int b = t >> 4, l = t & 15;
        const int swz = (b & 7) << 4;
        #pragma unroll
        for (int s = 0; s < 6; ++s) {
            *(u16x4*)(smem + 40960 + (s * 32 + b) * 256 + ((l * 8) ^ swz)) = f2bf4(nreg0[s]);
            *(u16x4*)(smem + 40960 + (s * 32 + b) * 256 + (((16 + l) * 8) ^ swz)) = f2bf4(nreg1[s]);
        }
    }
    __syncthreads();

    // ---- U2: obs_repr @ W1a + sub @ W1b (K=128 each), both m-tiles
    f32x4 u2[2], ac2[2];
    #pragma unroll
    for (int m = 0; m < 2; ++m) { u2[m] = (f32x4){0.f,0.f,0.f,0.f}; ac2[m] = (f32x4){0.f,0.f,0.f,0.f}; }
    #pragma unroll
    for (int kk = 0; kk < 4; ++kk) {
        s16x8 bfa = ldB8(W1, kk * 32 + g * 8, col);
        s16x8 bfb = ldB8(W1 + 128 * HH, kk * 32 + g * 8, col);
        #pragma unroll
        for (int m = 0; m < 2; ++m) {
            s16x8 afx = *(const s16x8*)(smem + 90112 + (m * 16 + r16) * 256 +
                                        ((kk * 64 + g * 16) ^ rswz));
            u2[m] = MFMA16(afx, bfa, u2[m]);
            s16x8 afs = *(const s16x8*)(smem + (m * 16 + r16) * 1280 +
                                        ((1024 + kk * 64 + g * 16) ^ rswz));
            ac2[m] = MFMA16(afs, bfb, ac2[m]);
        }
    }

    // ---- V: nodes @ W1c (K=128), B reused across 6 nodes x 2 m-tiles
    f32x4 v[2][6];
    #pragma unroll
    for (int m = 0; m < 2; ++m)
        #pragma unroll
        for (int s = 0; s < 6; ++s) v[m][s] = (f32x4){0.f, 0.f, 0.f, 0.f};
    #pragma unroll
    for (int kk = 0; kk < 4; ++kk) {
        s16x8 bf = ldB8(W1 + 256 * HH, kk * 32 + g * 8, col);
        #pragma unroll
        for (int m = 0; m < 2; ++m)
            #pragma unroll
            for (int s = 0; s < 6; ++s) {
                s16x8 af = *(const s16x8*)(smem + 40960 + (s * 32 + m * 16 + r16) * 256 +
                                           ((kk * 64 + g * 16) ^ rswz));
                v[m][s] = MFMA16(af, bf, v[m][s]);
            }
    }

    // ---- h fragments; sync (drain LDS reads) then overlay-write s_h
    float h[2][6][4];
    #pragma unroll
    for (int m = 0; m < 2; ++m)
        #pragma unroll
        for (int s = 0; s < 6; ++s)
            #pragma unroll
            for (int rg = 0; rg < 4; ++rg)
                h[m][s][rg] = u2[m][rg] + ac2[m][rg] + v[m][s][rg];
    __syncthreads();
    #pragma unroll
    for (int m = 0; m < 2; ++m)
        #pragma unroll
        for (int s = 0; s < 6; ++s)
            #pragma unroll
            for (int rg = 0; rg < 4; ++rg) {
                int bb = m * 16 + g * 4 + rg;
                s_h[(bb * 6 + s) * 133 + col] = h[m][s][rg];   // stride 133: bank=(5row+f)%32
            }
    __syncthreads();

    // ---- es/ed: 768 dots (b,i,hd), two per thread
    for (int idx = t; idx < 768; idx += NTHR) {
        int b = idx / 24, rem = idx - b * 24, i = rem >> 2, hd = rem & 3;
        const float* hrow = s_h + (b * 6 + i) * 133 + hd * 32;
        const float* as = a_src1 + hd * 32;
        const float* ad = a_dst1 + hd * 32;
        float ps = 0.f, pd = 0.f;
        #pragma unroll
        for (int f = 0; f < 32; ++f) {
            float hv = hrow[f];
            ps += hv * as[f];
            pd += hv * ad[f];
        }
        s_e[(b * 6 + i) * 8 + hd]     = ps;
        s_e[(b * 6 + i) * 8 + 4 + hd] = pd;
    }
    __syncthreads();

    // ---- layer-1 alphas: 768 softmax-6, two per thread
    for (int idx = t; idx < 768; idx += NTHR) {
        int b = idx / 24, rem = idx - b * 24, i = rem >> 2, hd = rem & 3;
        float ed = s_e[(b * 6 + i) * 8 + 4 + hd];
        float ev[6], mx = -1e30f;
        #pragma unroll
        for (int j = 0; j < 6; ++j) {
            float e = ed + s_e[(b * 6 + j) * 8 + hd];
            e = (e > 0.f) ? e : 0.2f * e;
            ev[j] = e; mx = fmaxf(mx, e);
        }
        float ex[6], ss = 0.f;
        #pragma unroll
        for (int j = 0; j < 6; ++j) { ex[j] = __expf(ev[j] - mx); ss += ex[j]; }
        float inv = 1.f / ss;
        #pragma unroll
        for (int j = 0; j < 6; ++j)
            s_alpha[b * 145 + i * 24 + hd * 6 + j] = ex[j] * inv;
    }
    __syncthreads();

    // ---- aggregation (reg h) + b1 + ELU + *W2 + 16-lane reduce -> s_p
    {
        const int hd = w >> 1;
        float b1v = b1[col], w2v = W2[col];
        #pragma unroll
        for (int m = 0; m < 2; ++m)
            #pragma unroll
            for (int i = 0; i < 6; ++i)
                #pragma unroll
                for (int rg = 0; rg < 4; ++rg) {
                    int bb = m * 16 + g * 4 + rg;
                    const float* al = s_alpha + bb * 145 + i * 24 + hd * 6;
                    float acc = al[0] * h[m][0][rg] + al[1] * h[m][1][rg] +
                                al[2] * h[m][2][rg] + al[3] * h[m][3][rg] +
                                al[4] * h[m][4][rg] + al[5] * h[m][5][rg];
                    float o = acc + b1v;
                    o = (o > 0.f) ? o : __expf(o) - 1.f;   // ELU
                    float p = o * w2v;
                    p += __shfl_xor(p, 1); p += __shfl_xor(p, 2);
                    p += __shfl_xor(p, 4); p += __shfl_xor(p, 8);
                    if (r16 == 0) s_p[(w * 32 + bb) * 6 + i] = p;
                }
    }
    __syncthreads();

    // ---- combine h2 + layer-2 GAT + write (192 threads: one (b,i) each)
    if (t < 192) {
        int b = t / 6, i = t - b * 6;
        float hh[6];
        #pragma unroll
        for (int j = 0; j < 6; ++j) {
            float acc = 0.f;
            #pragma unroll
            for (int ww = 0; ww < 8; ++ww) acc += s_p[(ww * 32 + b) * 6 + j];
            hh[j] = acc;
        }
        float as2v = a_src2[0], ad2v = a_dst2[0];
        float hi = hh[i];
        float ev[6], mx = -1e30f;
        #pragma unroll
        for (int j = 0; j < 6; ++j) {
            float e = ad2v * hi + as2v * hh[j];
            e = (e > 0.f) ? e : 0.2f * e;
            ev[j] = e; mx = fmaxf(mx, e);
        }
        float ss = 0.f, acc = 0.f;
        #pragma unroll
        for (int j = 0; j < 6; ++j) {
            float ex = __expf(ev[j] - mx);
            ss += ex; acc += ex * hh[j];
        }
        out[(gb0 + b) * 6 + i] = acc / ss + b2[0];
    }
}

extern "C" void kernel_launch(void* const* d_in, const int* in_sizes, int n_in,
                              void* d_out, int out_size, void* d_ws, size_t ws_size,
                              hipStream_t stream) {
    const float* org_obs    = (const float*)d_in[0];
    const float* node_emb   = (const float*)d_in[1];
    const float* subst      = (const float*)d_in[2];
    const int*   sub_choice = (const int*)d_in[3];
    const int*   sub_map    = (const int*)d_in[4];
    const float* Wproj      = (const float*)d_in[5];
    const float* bproj      = (const float*)d_in[6];
    const float* W1         = (const float*)d_in[7];
    const float* a_src1     = (const float*)d_in[8];
    const float* a_dst1     = (const float*)d_in[9];
    const float* b1         = (const float*)d_in[10];
    const float* W2         = (const float*)d_in[11];
    const float* a_src2     = (const float*)d_in[12];
    const float* a_dst2     = (const float*)d_in[13];
    const float* b2         = (const float*)d_in[14];

    hipLaunchKernelGGL(k_main, dim3(BB / TB), dim3(NTHR), 0, stream,
                       org_obs, node_emb, subst, sub_choice, sub_map,
                       Wproj, bproj, W1, a_src1, a_dst1, b1, W2,
                       a_src2, a_dst2, b2, (float*)d_out);
}

// Round 6
// 23.470 us; speedup vs baseline: 1.3484x; 1.3484x over previous
//
#include <hip/hip_runtime.h>

// Problem constants
#define BB     4096
#define NNODE  177
#define NSUB   36
#define KN     6
#define HH     128
#define OBSD   500
#define TB     16          // batches per block = MFMA M (all rows real)
#define NTHR   512         // 8 waves, 2/SIMD; grid = 256 = 1 block/CU

typedef unsigned short ushort_t;
typedef __attribute__((ext_vector_type(4))) float f32x4;
typedef __attribute__((ext_vector_type(8))) short s16x8;
typedef __attribute__((ext_vector_type(4))) unsigned short u16x4;

#define MFMA16(a, b, c) __builtin_amdgcn_mfma_f32_16x16x32_bf16((a), (b), (c), 0, 0, 0)

// LDS offsets (bytes)
#define S_A      0          // [16][1280B] bf16 swz (obs 0..499|0|sub 512..639) = 20480
#define S_NODES  20480      // [6][16][256B] bf16 swz = 24576
#define S_X      45056      // [16][256B] bf16 swz = 4096
#define S_H      49152      // f32 [96][stride 133] = 51072  (bank scramble: 133%32=5)
#define S_E      100224     // f32 [96][stride 9]   = 3456   (0-3 es, 4-7 ed)
#define S_ALPHA  103680     // f32 [16*145]         = 9280
#define S_P      112960     // f32 [8][16][6]       = 3072
#define SMEM_SZ  116032

__device__ __forceinline__ ushort_t f2bf(float f) {
    unsigned u = __float_as_uint(f);
    u += 0x7FFFu + ((u >> 16) & 1u);   // RNE
    return (ushort_t)(u >> 16);
}
__device__ __forceinline__ u16x4 f2bf4(float4 v) {
    u16x4 o; o.x = f2bf(v.x); o.y = f2bf(v.y); o.z = f2bf(v.z); o.w = f2bf(v.w);
    return o;
}

// B-fragment on the fly: bf16x8 of W[(k+j)*128 + col], j=0..7 (column slice;
// 16 lanes of a g-group cover one 64B L2 line per j). RNE via v_cvt_pk_bf16_f32.
__device__ __forceinline__ s16x8 ldB8(const float* __restrict__ W, int k, int col) {
    const float* p = W + k * HH + col;
    float w0 = p[0],      w1 = p[HH],     w2 = p[2 * HH], w3 = p[3 * HH];
    float w4 = p[4 * HH], w5 = p[5 * HH], w6 = p[6 * HH], w7 = p[7 * HH];
    union { unsigned u[4]; s16x8 v; } U;
    asm("v_cvt_pk_bf16_f32 %0, %1, %2" : "=v"(U.u[0]) : "v"(w0), "v"(w1));
    asm("v_cvt_pk_bf16_f32 %0, %1, %2" : "=v"(U.u[1]) : "v"(w2), "v"(w3));
    asm("v_cvt_pk_bf16_f32 %0, %1, %2" : "=v"(U.u[2]) : "v"(w4), "v"(w5));
    asm("v_cvt_pk_bf16_f32 %0, %1, %2" : "=v"(U.u[3]) : "v"(w6), "v"(w7));
    return U.v;
}
__device__ __forceinline__ s16x8 ldB8m(const float* __restrict__ W, int k, int col, int kmax) {
    float w[8];
    #pragma unroll
    for (int j = 0; j < 8; ++j) w[j] = (k + j < kmax) ? W[(k + j) * HH + col] : 0.f;
    union { unsigned u[4]; s16x8 v; } U;
    #pragma unroll
    for (int j = 0; j < 4; ++j)
        asm("v_cvt_pk_bf16_f32 %0, %1, %2" : "=v"(U.u[j]) : "v"(w[2 * j]), "v"(w[2 * j + 1]));
    return U.v;
}

// ---------------------------------------------------------------------------
// Single fused kernel (r4 structure). Block = 16 batches, 8 waves; wave w
// owns cols [16w,16w+16). Weights consumed directly from f32 global (L2-hot),
// converted in-register. This round: bank-conflict-free s_h/s_e phases.
// ---------------------------------------------------------------------------
__global__ void __launch_bounds__(NTHR, 2) k_main(
    const float* __restrict__ org_obs, const float* __restrict__ node_emb,
    const float* __restrict__ subst,   const int* __restrict__ sub_choice,
    const int* __restrict__ sub_map,   const float* __restrict__ Wproj,
    const float* __restrict__ bproj,   const float* __restrict__ W1,
    const float* __restrict__ a_src1,  const float* __restrict__ a_dst1,
    const float* __restrict__ b1,      const float* __restrict__ W2,
    const float* __restrict__ a_src2,  const float* __restrict__ a_dst2,
    const float* __restrict__ b2,      float* __restrict__ out) {

    __shared__ __align__(16) char smem[SMEM_SZ];
    float* s_h     = (float*)(smem + S_H);
    float* s_e     = (float*)(smem + S_E);
    float* s_alpha = (float*)(smem + S_ALPHA);
    float* s_p     = (float*)(smem + S_P);

    const int t   = threadIdx.x;
    const int gb0 = blockIdx.x * TB;

    // ---- staging: obs+sub -> s_a (swz); nodes -> regs (write after phase1)
    float4 nreg[6];
    {
        const int b = t >> 5, l = t & 31;
        const float* orow = org_obs + (size_t)(gb0 + b) * OBSD;
        int sub = sub_choice[gb0 + b];
        const int* emap = sub_map + sub * KN;
        #pragma unroll
        for (int s = 0; s < 6; ++s)
            nreg[s] = ((const float4*)(node_emb +
                        ((size_t)(gb0 + b) * NNODE + emap[s]) * HH))[l];
        const int swz = (b & 7) << 4;
        #pragma unroll
        for (int it = 0; it < 4; ++it) {
            int idx = it * 32 + l;
            u16x4 v = {0, 0, 0, 0};
            if (idx < 125) v = f2bf4(((const float4*)orow)[idx]);
            *(u16x4*)(smem + b * 1280 + ((idx * 8) ^ swz)) = v;
        }
        const float* srow = subst + ((size_t)(gb0 + b) * NSUB + sub) * HH;
        *(u16x4*)(smem + b * 1280 + ((1024 + l * 8) ^ swz)) = f2bf4(((const float4*)srow)[l]);
    }
    __syncthreads();

    const int w = t >> 6, ln = t & 63, r16 = ln & 15, g = ln >> 4;
    const int col = w * 16 + r16;
    const int rswz = (r16 & 7) << 4;

    // ---- phase 1: obs @ Wproj (K=512, rows 500..511 masked)
    f32x4 acc1 = {0.f, 0.f, 0.f, 0.f};
    #pragma unroll 5
    for (int kk = 0; kk < 15; ++kk) {
        s16x8 af = *(const s16x8*)(smem + r16 * 1280 + ((kk * 64 + g * 16) ^ rswz));
        s16x8 bf = ldB8(Wproj, kk * 32 + g * 8, col);
        acc1 = MFMA16(af, bf, acc1);
    }
    {
        s16x8 af = *(const s16x8*)(smem + r16 * 1280 + ((15 * 64 + g * 16) ^ rswz));
        s16x8 bf = ldB8m(Wproj, 15 * 32 + g * 8, col, OBSD);
        acc1 = MFMA16(af, bf, acc1);
    }

    // ---- obs_repr(+bproj) -> s_x bf16; node regs -> s_nodes
    {
        float bp = bproj[col];
        #pragma unroll
        for (int rg = 0; rg < 4; ++rg) {
            int bb = g * 4 + rg;
            *(ushort_t*)(smem + S_X + bb * 256 + ((col * 2) ^ ((bb & 7) << 4))) =
                f2bf(acc1[rg] + bp);
        }
    }
    {
        const int b = t >> 5, l = t & 31;
        const int swz = (b & 7) << 4;
        #pragma unroll
        for (int s = 0; s < 6; ++s)
            *(u16x4*)(smem + S_NODES + (s * 16 + b) * 256 + ((l * 8) ^ swz)) =
                f2bf4(nreg[s]);
    }
    __syncthreads();

    // ---- U2: obs_repr @ W1a (rows 0..127) + sub @ W1b (rows 128..255)
    f32x4 u2 = {0.f, 0.f, 0.f, 0.f}, acc2 = {0.f, 0.f, 0.f, 0.f};
    #pragma unroll
    for (int kk = 0; kk < 4; ++kk) {
        s16x8 afx = *(const s16x8*)(smem + S_X + r16 * 256 + ((kk * 64 + g * 16) ^ rswz));
        s16x8 bfx = ldB8(W1, kk * 32 + g * 8, col);
        u2 = MFMA16(afx, bfx, u2);
        s16x8 afs = *(const s16x8*)(smem + r16 * 1280 + ((1024 + kk * 64 + g * 16) ^ rswz));
        s16x8 bfs = ldB8(W1 + 128 * HH, kk * 32 + g * 8, col);
        acc2 = MFMA16(afs, bfs, acc2);
    }

    // ---- V: nodes @ W1c (rows 256..383), B reused across 6 nodes
    f32x4 v[6];
    #pragma unroll
    for (int s = 0; s < 6; ++s) v[s] = (f32x4){0.f, 0.f, 0.f, 0.f};
    #pragma unroll
    for (int kk = 0; kk < 4; ++kk) {
        s16x8 bf = ldB8(W1 + 256 * HH, kk * 32 + g * 8, col);
        #pragma unroll
        for (int s = 0; s < 6; ++s) {
            s16x8 af = *(const s16x8*)(smem + S_NODES + (s * 16 + r16) * 256 +
                                       ((kk * 64 + g * 16) ^ rswz));
            v[s] = MFMA16(af, bf, v[s]);
        }
    }

    // ---- h fragments + write s_h (f32, stride 133 -> bank scramble 5r)
    float h[6][4];
    #pragma unroll
    for (int s = 0; s < 6; ++s)
        #pragma unroll
        for (int rg = 0; rg < 4; ++rg) {
            h[s][rg] = u2[rg] + acc2[rg] + v[s][rg];
            s_h[((g * 4 + rg) * 6 + s) * 133 + col] = h[s][rg];
        }
    __syncthreads();

    // ---- es/ed: 384 threads, two 32-MAC dots each; rotated start index
    // bank = (9q + s + ff) mod 32 over the wave -> worst 2-way (free)
    if (t < 384) {
        int b = t / 24, rem = t - b * 24, i = rem >> 2, hd = rem & 3;
        const float* hrow = s_h + (b * 6 + i) * 133 + hd * 32;
        const float* as = a_src1 + hd * 32;
        const float* ad = a_dst1 + hd * 32;
        const int f0 = t & 31;
        float ps = 0.f, pd = 0.f;
        #pragma unroll
        for (int ff = 0; ff < 32; ++ff) {
            int f = (f0 + ff) & 31;
            float hv = hrow[f];
            ps += hv * as[f];
            pd += hv * ad[f];
        }
        s_e[(b * 6 + i) * 9 + hd]     = ps;
        s_e[(b * 6 + i) * 9 + 4 + hd] = pd;
    }
    __syncthreads();

    // ---- layer-1 alphas: 384 threads, one softmax-6 each
    if (t < 384) {
        int b = t / 24, rem = t - b * 24, i = rem >> 2, hd = rem & 3;
        float ed = s_e[(b * 6 + i) * 9 + 4 + hd];
        float ev[6], mx = -1e30f;
        #pragma unroll
        for (int j = 0; j < 6; ++j) {
            float e = ed + s_e[(b * 6 + j) * 9 + hd];
            e = (e > 0.f) ? e : 0.2f * e;
            ev[j] = e; mx = fmaxf(mx, e);
        }
        float ex[6], ss = 0.f;
        #pragma unroll
        for (int j = 0; j < 6; ++j) { ex[j] = __expf(ev[j] - mx); ss += ex[j]; }
        float inv = 1.f / ss;
        #pragma unroll
        for (int j = 0; j < 6; ++j)
            s_alpha[b * 145 + i * 24 + hd * 6 + j] = ex[j] * inv;
    }
    __syncthreads();

    // ---- aggregation (reg h) + b1 + ELU + *W2 + 16-lane reduce -> s_p
    {
        const int hd = w >> 1;
        float b1v = b1[col], w2v = W2[col];
        #pragma unroll
        for (int i = 0; i < 6; ++i)
            #pragma unroll
            for (int rg = 0; rg < 4; ++rg) {
                int bb = g * 4 + rg;
                const float* al = s_alpha + bb * 145 + i * 24 + hd * 6;
                float acc = al[0] * h[0][rg] + al[1] * h[1][rg] + al[2] * h[2][rg] +
                            al[3] * h[3][rg] + al[4] * h[4][rg] + al[5] * h[5][rg];
                float o = acc + b1v;
                o = (o > 0.f) ? o : __expf(o) - 1.f;   // ELU
                float p = o * w2v;
                p += __shfl_xor(p, 1); p += __shfl_xor(p, 2);
                p += __shfl_xor(p, 4); p += __shfl_xor(p, 8);
                if (r16 == 0) s_p[(w * 16 + bb) * 6 + i] = p;
            }
    }
    __syncthreads();

    // ---- combine h2 + layer-2 GAT + write
    if (t < 96) {
        int b = t / 6, i = t - b * 6;
        float hh[6];
        #pragma unroll
        for (int j = 0; j < 6; ++j) {
            float acc = 0.f;
            #pragma unroll
            for (int ww = 0; ww < 8; ++ww) acc += s_p[(ww * 16 + b) * 6 + j];
            hh[j] = acc;
        }
        float as2v = a_src2[0], ad2v = a_dst2[0];
        float hi = hh[i];
        float ev[6], mx = -1e30f;
        #pragma unroll
        for (int j = 0; j < 6; ++j) {
            float e = ad2v * hi + as2v * hh[j];
            e = (e > 0.f) ? e : 0.2f * e;
            ev[j] = e; mx = fmaxf(mx, e);
        }
        float ss = 0.f, acc = 0.f;
        #pragma unroll
        for (int j = 0; j < 6; ++j) {
            float ex = __expf(ev[j] - mx);
            ss += ex; acc += ex * hh[j];
        }
        out[(gb0 + b) * 6 + i] = acc / ss + b2[0];
    }
}

extern "C" void kernel_launch(void* const* d_in, const int* in_sizes, int n_in,
                              void* d_out, int out_size, void* d_ws, size_t ws_size,
                              hipStream_t stream) {
    const float* org_obs    = (const float*)d_in[0];
    const float* node_emb   = (const float*)d_in[1];
    const float* subst      = (const float*)d_in[2];
    const int*   sub_choice = (const int*)d_in[3];
    const int*   sub_map    = (const int*)d_in[4];
    const float* Wproj      = (const float*)d_in[5];
    const float* bproj      = (const float*)d_in[6];
    const float* W1         = (const float*)d_in[7];
    const float* a_src1     = (const float*)d_in[8];
    const float* a_dst1     = (const float*)d_in[9];
    const float* b1         = (const float*)d_in[10];
    const float* W2         = (const float*)d_in[11];
    const float* a_src2     = (const float*)d_in[12];
    const float* a_dst2     = (const float*)d_in[13];
    const float* b2         = (const float*)d_in[14];

    hipLaunchKernelGGL(k_main, dim3(BB / TB), dim3(NTHR), 0, stream,
                       org_obs, node_emb, subst, sub_choice, sub_map,
                       Wproj, bproj, W1, a_src1, a_dst1, b1, W2,
                       a_src2, a_dst2, b2, (float*)d_out);
}